// Round 7
// baseline (209.915 us; speedup 1.0000x reference)
//
#include <hip/hip_runtime.h>
#include <hip/hip_bf16.h>

#define HID 64
#define SST 132   // slds row stride in ushorts (264B: breaks pow2 banks, 8B-aligned rows)

typedef __attribute__((ext_vector_type(8))) short bf16x8;
typedef __attribute__((ext_vector_type(4))) float f32x4;

__device__ __forceinline__ unsigned short f2bf(float f) {
    unsigned int u = __float_as_uint(f);
    return (unsigned short)((u + 0x7fffu + ((u >> 16) & 1u)) >> 16);
}

__device__ __forceinline__ unsigned int pack2bf(float lo, float hi) {
    unsigned int ul = __float_as_uint(lo), uh = __float_as_uint(hi);
    unsigned int rl = (ul + 0x7fffu + ((ul >> 16) & 1u)) >> 16;
    unsigned int rh = (uh + 0x7fffu + ((uh >> 16) & 1u)) & 0xffff0000u;
    return rl | rh;
}

// W1bt[c][k] = bf16(W1[(c>=64 ? 64 : 0) + k][c & 63]), c=0..127, k=0..63.
__global__ __launch_bounds__(256) void prep_weights(
    const float* __restrict__ W1, unsigned short* __restrict__ W1bt)
{
    const int t = blockIdx.x * 256 + threadIdx.x;   // 8192
    const int c = t >> 6, k = t & 63;
    W1bt[t] = f2bf(W1[(((c >> 6) << 6) + k) * HID + (c & 63)]);
}

// Node projection with COALESCED stores.
// C[100000 x 128] = z[100000 x 64] @ [W1a | W1b]; cols 0-63 -> A, 64-127 -> B(+b1).
// One block = 4 waves = 64 nodes, one shot. MFMA accs are staged through LDS
// ([64][SST] ushort) and written out as full 128B lines (16B per thread,
// consecutive threads -> consecutive 16B).
__global__ __launch_bounds__(256) void node_proj_mfma(
    const float* __restrict__ z, const unsigned short* __restrict__ W1bt,
    const float* __restrict__ b1,
    unsigned short* __restrict__ A, unsigned short* __restrict__ B,
    int n_nodes)
{
    __shared__ alignas(16) unsigned short slds[64 * SST];

    const int t    = threadIdx.x;
    const int lane = t & 63;
    const int wv   = t >> 6;         // 0..3
    const int q    = lane >> 4;      // k-group
    const int r    = lane & 15;      // A row / B col within tile
    const int base = blockIdx.x * 64;

    // weight fragments straight from global (L2-resident, 16B/lane)
    bf16x8 wf[8][2];
#pragma unroll
    for (int ct = 0; ct < 8; ++ct)
#pragma unroll
        for (int ks = 0; ks < 2; ++ks)
            wf[ct][ks] = *(const bf16x8*)(W1bt + (ct * 16 + r) * HID + ks * 32 + q * 8);

    float bias[4];
#pragma unroll
    for (int i = 0; i < 4; ++i) bias[i] = b1[i * 16 + r];

    // A-operand: lane holds bf16(z[rowb + r][ks*32 + q*8 + i]), i=0..7
    const int rowb = base + wv * 16;
    int zrow = rowb + r;
    if (zrow >= n_nodes) zrow = n_nodes - 1;
    const float* zb = z + (size_t)zrow * HID;
    bf16x8 af[2];
#pragma unroll
    for (int ks = 0; ks < 2; ++ks) {
        const float4 f0 = *(const float4*)(zb + ks * 32 + q * 8);
        const float4 f1 = *(const float4*)(zb + ks * 32 + q * 8 + 4);
        unsigned int u[4];
        u[0] = pack2bf(f0.x, f0.y); u[1] = pack2bf(f0.z, f0.w);
        u[2] = pack2bf(f1.x, f1.y); u[3] = pack2bf(f1.z, f1.w);
        af[ks] = *(bf16x8*)u;
    }

#pragma unroll
    for (int ct = 0; ct < 8; ++ct) {
        f32x4 acc = {0.f, 0.f, 0.f, 0.f};
        acc = __builtin_amdgcn_mfma_f32_16x16x32_bf16(af[0], wf[ct][0], acc, 0, 0, 0);
        acc = __builtin_amdgcn_mfma_f32_16x16x32_bf16(af[1], wf[ct][1], acc, 0, 0, 0);
        const float bv = (ct >= 4) ? bias[ct & 3] : 0.0f;
        const int c = ct * 16 + r;            // combined col 0..127
        // C/D map (HW-verified): col = lane&15, row = (lane>>4)*4 + reg
#pragma unroll
        for (int j = 0; j < 4; ++j) {
            const int nl = wv * 16 + q * 4 + j;   // node-local 0..63
            slds[nl * SST + c] = f2bf(acc[j] + bv);
        }
    }
    __syncthreads();

    // coalesced write-out: flat uint4 id i -> node i>>3, 16B segment i&7
#pragma unroll
    for (int rep = 0; rep < 2; ++rep) {
        const int i   = t + rep * 256;        // 0..511
        const int nl  = i >> 3, seg = i & 7;
        const int ng  = base + nl;
        if (ng < n_nodes) {
            const uint2* pa = (const uint2*)(slds + nl * SST + seg * 8);
            const uint2* pb = (const uint2*)(slds + nl * SST + 64 + seg * 8);
            uint4 va, vb;
            va.x = pa[0].x; va.y = pa[0].y; va.z = pa[1].x; va.w = pa[1].y;
            vb.x = pb[0].x; vb.y = pb[0].y; vb.z = pb[1].x; vb.w = pb[1].y;
            *(uint4*)(A + (size_t)ng * HID + seg * 8) = va;
            *(uint4*)(B + (size_t)ng * HID + seg * 8) = vb;
        }
    }
}

// Edge kernel (control, range-split for profiler visibility):
// out[e] = relu(A[row[e]] + B[col[e]]) . W2 + b2
__global__ __launch_bounds__(256) void edge_kernel(
    const int* __restrict__ row, const int* __restrict__ col,
    const unsigned short* __restrict__ A, const unsigned short* __restrict__ B,
    const float* __restrict__ W2, const float* __restrict__ b2,
    float* __restrict__ out, int cbegin, int cend)
{
    const int tid    = blockIdx.x * blockDim.x + threadIdx.x;
    const int lane   = tid & 63;
    const int gwave  = tid >> 6;
    const int nwaves = (gridDim.x * blockDim.x) >> 6;
    const int sub    = lane >> 3;   // 0..7: which edge of the group of 8
    const int l8     = lane & 7;    // dim slice: dims l8*8 .. l8*8+7

    float w2r[8];
#pragma unroll
    for (int i = 0; i < 8; ++i) w2r[i] = W2[l8 * 8 + i];
    const float b2v = b2[0];

    for (int ch = cbegin + gwave; ch < cend; ch += nwaves) {
        const int ebase = ch << 6;
        const int r = row[ebase + lane];   // coalesced
        const int c = col[ebase + lane];

        uint4 av[8], bv[8];
#pragma unroll
        for (int g = 0; g < 8; ++g) {
            const int ri = __shfl(r, g * 8 + sub);
            const int ci = __shfl(c, g * 8 + sub);
            av[g] = *(const uint4*)(A + (size_t)ri * HID + l8 * 8);
            bv[g] = *(const uint4*)(B + (size_t)ci * HID + l8 * 8);
        }

#pragma unroll
        for (int g = 0; g < 8; ++g) {
            const unsigned int* au = (const unsigned int*)&av[g];
            const unsigned int* bu = (const unsigned int*)&bv[g];
            float acc = 0.f;
#pragma unroll
            for (int i = 0; i < 4; ++i) {
                float alo = __uint_as_float(au[i] << 16);
                float ahi = __uint_as_float(au[i] & 0xffff0000u);
                float blo = __uint_as_float(bu[i] << 16);
                float bhi = __uint_as_float(bu[i] & 0xffff0000u);
                acc = fmaf(fmaxf(alo + blo, 0.f), w2r[2 * i + 0], acc);
                acc = fmaf(fmaxf(ahi + bhi, 0.f), w2r[2 * i + 1], acc);
            }
            acc += __shfl_xor(acc, 4);
            acc += __shfl_xor(acc, 2);
            acc += __shfl_xor(acc, 1);
            if (l8 == 0) out[ebase + g * 8 + sub] = acc + b2v;
        }
    }
}

extern "C" void kernel_launch(void* const* d_in, const int* in_sizes, int n_in,
                              void* d_out, int out_size, void* d_ws, size_t ws_size,
                              hipStream_t stream) {
    const float* z  = (const float*)d_in[0];
    const int*   ei = (const int*)d_in[1];
    const float* W1 = (const float*)d_in[2];
    const float* b1 = (const float*)d_in[3];
    const float* W2 = (const float*)d_in[4];
    const float* b2 = (const float*)d_in[5];
    float* out = (float*)d_out;

    const int n_nodes = in_sizes[0] / HID;     // 100000
    const int E       = in_sizes[1] / 2;       // 3200000
    const int* row = ei;
    const int* col = ei + E;

    unsigned short* A = (unsigned short*)d_ws;         // [n_nodes][64] bf16 (128B rows)
    unsigned short* B = A + (size_t)n_nodes * HID;     // [n_nodes][64] bf16
    unsigned short* W1bt = B + (size_t)n_nodes * HID;  // 128*64 bf16

    prep_weights<<<32, 256, 0, stream>>>(W1, W1bt);
    const int nblocks = (n_nodes + 63) / 64;           // 1563, one shot
    node_proj_mfma<<<nblocks, 256, 0, stream>>>(z, W1bt, b1, A, B, n_nodes);

    const int nchunks = E >> 6;                        // 50000
    const int half = nchunks / 2;
    edge_kernel<<<2048, 256, 0, stream>>>(row, col, A, B, W2, b2, out, 0, half);
    edge_kernel<<<2048, 256, 0, stream>>>(row, col, A, B, W2, b2, out, half, nchunks);
}

// Round 8
// 205.820 us; speedup vs baseline: 1.0199x; 1.0199x over previous
//
#include <hip/hip_runtime.h>
#include <hip/hip_bf16.h>

#define HID 64
#define SST 136   // staging row stride in ushorts: 272B (16B-aligned rows, 68 dw -> bases step 4)

typedef __attribute__((ext_vector_type(8))) short bf16x8;
typedef __attribute__((ext_vector_type(4))) float f32x4;

__device__ __forceinline__ unsigned short f2bf(float f) {
    unsigned int u = __float_as_uint(f);
    return (unsigned short)((u + 0x7fffu + ((u >> 16) & 1u)) >> 16);
}

__device__ __forceinline__ unsigned int pack2bf(float lo, float hi) {
    unsigned int ul = __float_as_uint(lo), uh = __float_as_uint(hi);
    unsigned int rl = (ul + 0x7fffu + ((ul >> 16) & 1u)) >> 16;
    unsigned int rh = (uh + 0x7fffu + ((uh >> 16) & 1u)) & 0xffff0000u;
    return rl | rh;
}

// Node projection, wave-autonomous: each wave owns 64 nodes (4 tiles of 16),
// no block barrier. Weight fragments are built once per wave straight from W1
// (L2-resident after first touch) and amortized over 4 tiles. Per tile:
// z loads -> pack bf16 -> 16x mfma_f32_16x16x32_bf16 -> stage to this wave's
// LDS slice (XOR-swizzled, conflict-free) -> coalesced 16B global stores.
// C[n][c], c=0..127: c<64 -> A (no bias), c>=64 -> B (+b1).
__global__ __launch_bounds__(256) void node_proj_mfma(
    const float* __restrict__ z, const float* __restrict__ W1,
    const float* __restrict__ b1,
    unsigned short* __restrict__ A, unsigned short* __restrict__ B,
    int n_nodes)
{
    __shared__ alignas(16) unsigned short slds[4 * 16 * SST];   // 4 waves x 16 rows

    const int t    = threadIdx.x;
    const int lane = t & 63;
    const int wv   = t >> 6;          // 0..3
    const int q    = lane >> 4;       // k-group
    const int r    = lane & 15;       // A-row / B-col within tile
    const int gw   = blockIdx.x * 4 + wv;   // global wave id; nodes [gw*64, gw*64+64)

    unsigned short* __restrict__ sub = slds + wv * 16 * SST;

    // Weight fragments from W1 [128][64] f32: for output col c = ct*16 + r,
    // k = ks*32 + q*8 + i:  W1[(c>=64?64:0) + k][c & 63]
    bf16x8 wf[8][2];
#pragma unroll
    for (int ct = 0; ct < 8; ++ct) {
        const int hof = (ct >= 4) ? 64 : 0;
        const int cw  = (ct & 3) * 16 + r;
#pragma unroll
        for (int ks = 0; ks < 2; ++ks) {
            unsigned short tmp[8];
#pragma unroll
            for (int i = 0; i < 8; ++i)
                tmp[i] = f2bf(W1[(hof + ks * 32 + q * 8 + i) * HID + cw]);
            wf[ct][ks] = *(bf16x8*)tmp;
        }
    }

    float bias[4];
#pragma unroll
    for (int i = 0; i < 4; ++i) bias[i] = b1[i * 16 + r];

#pragma unroll
    for (int tt = 0; tt < 4; ++tt) {
        const int rowb = gw * 64 + tt * 16;
        int zrow = rowb + r;
        if (zrow >= n_nodes) zrow = n_nodes - 1;
        const float* zb = z + (size_t)zrow * HID;

        bf16x8 af[2];
#pragma unroll
        for (int ks = 0; ks < 2; ++ks) {
            const float4 f0 = *(const float4*)(zb + ks * 32 + q * 8);
            const float4 f1 = *(const float4*)(zb + ks * 32 + q * 8 + 4);
            unsigned int u[4];
            u[0] = pack2bf(f0.x, f0.y); u[1] = pack2bf(f0.z, f0.w);
            u[2] = pack2bf(f1.x, f1.y); u[3] = pack2bf(f1.z, f1.w);
            af[ks] = *(bf16x8*)u;
        }

#pragma unroll
        for (int ct = 0; ct < 8; ++ct) {
            f32x4 acc = {0.f, 0.f, 0.f, 0.f};
            acc = __builtin_amdgcn_mfma_f32_16x16x32_bf16(af[0], wf[ct][0], acc, 0, 0, 0);
            acc = __builtin_amdgcn_mfma_f32_16x16x32_bf16(af[1], wf[ct][1], acc, 0, 0, 0);
            const float bv = (ct >= 4) ? bias[ct & 3] : 0.0f;
            // C/D map (HW-verified): col = lane&15, row = (lane>>4)*4 + reg
#pragma unroll
            for (int j = 0; j < 4; ++j) {
                const int rl = q * 4 + j;                 // tile-local node 0..15
                const int cx = (ct * 16 + r) ^ ((rl & 8) ? 32 : 0);  // swizzle
                sub[rl * SST + cx] = f2bf(acc[j] + bv);
            }
        }
        // same-wave LDS dependency: compiler inserts lgkmcnt before ds_read.

        // coalesced writeout: 2 instrs per array; 8 lanes x 16B per node row
#pragma unroll
        for (int p = 0; p < 2; ++p) {
            const int flat = p * 64 + lane;
            const int nl   = flat >> 3;                  // tile-local node 0..15
            const int s    = flat & 7;                   // 16B segment
            const int ng   = rowb + nl;
            const int xr   = (nl & 8) ? 32 : 0;
            const uint4 va = *(const uint4*)(sub + nl * SST + ((s * 8) ^ xr));
            const uint4 vb = *(const uint4*)(sub + nl * SST + ((64 + s * 8) ^ xr));
            if (ng < n_nodes) {
                *(uint4*)(A + (size_t)ng * HID + s * 8) = va;
                *(uint4*)(B + (size_t)ng * HID + s * 8) = vb;
            }
        }
    }
}

// Edge kernel (control, unequal range-split for profiler visibility):
// out[e] = relu(A[row[e]] + B[col[e]]) . W2 + b2
__global__ __launch_bounds__(256) void edge_kernel(
    const int* __restrict__ row, const int* __restrict__ col,
    const unsigned short* __restrict__ A, const unsigned short* __restrict__ B,
    const float* __restrict__ W2, const float* __restrict__ b2,
    float* __restrict__ out, int cbegin, int cend)
{
    const int tid    = blockIdx.x * blockDim.x + threadIdx.x;
    const int lane   = tid & 63;
    const int gwave  = tid >> 6;
    const int nwaves = (gridDim.x * blockDim.x) >> 6;
    const int sub    = lane >> 3;   // 0..7: which edge of the group of 8
    const int l8     = lane & 7;    // dim slice: dims l8*8 .. l8*8+7

    float w2r[8];
#pragma unroll
    for (int i = 0; i < 8; ++i) w2r[i] = W2[l8 * 8 + i];
    const float b2v = b2[0];

    for (int ch = cbegin + gwave; ch < cend; ch += nwaves) {
        const int ebase = ch << 6;
        const int r = row[ebase + lane];   // coalesced
        const int c = col[ebase + lane];

        uint4 av[8], bv[8];
#pragma unroll
        for (int g = 0; g < 8; ++g) {
            const int ri = __shfl(r, g * 8 + sub);
            const int ci = __shfl(c, g * 8 + sub);
            av[g] = *(const uint4*)(A + (size_t)ri * HID + l8 * 8);
            bv[g] = *(const uint4*)(B + (size_t)ci * HID + l8 * 8);
        }

#pragma unroll
        for (int g = 0; g < 8; ++g) {
            const unsigned int* au = (const unsigned int*)&av[g];
            const unsigned int* bu = (const unsigned int*)&bv[g];
            float acc = 0.f;
#pragma unroll
            for (int i = 0; i < 4; ++i) {
                float alo = __uint_as_float(au[i] << 16);
                float ahi = __uint_as_float(au[i] & 0xffff0000u);
                float blo = __uint_as_float(bu[i] << 16);
                float bhi = __uint_as_float(bu[i] & 0xffff0000u);
                acc = fmaf(fmaxf(alo + blo, 0.f), w2r[2 * i + 0], acc);
                acc = fmaf(fmaxf(ahi + bhi, 0.f), w2r[2 * i + 1], acc);
            }
            acc += __shfl_xor(acc, 4);
            acc += __shfl_xor(acc, 2);
            acc += __shfl_xor(acc, 1);
            if (l8 == 0) out[ebase + g * 8 + sub] = acc + b2v;
        }
    }
}

extern "C" void kernel_launch(void* const* d_in, const int* in_sizes, int n_in,
                              void* d_out, int out_size, void* d_ws, size_t ws_size,
                              hipStream_t stream) {
    const float* z  = (const float*)d_in[0];
    const int*   ei = (const int*)d_in[1];
    const float* W1 = (const float*)d_in[2];
    const float* b1 = (const float*)d_in[3];
    const float* W2 = (const float*)d_in[4];
    const float* b2 = (const float*)d_in[5];
    float* out = (float*)d_out;

    const int n_nodes = in_sizes[0] / HID;     // 100000
    const int E       = in_sizes[1] / 2;       // 3200000
    const int* row = ei;
    const int* col = ei + E;

    unsigned short* A = (unsigned short*)d_ws;         // [n_nodes][64] bf16 (128B rows)
    unsigned short* B = A + (size_t)n_nodes * HID;     // [n_nodes][64] bf16

    const int nblocks = (n_nodes + 255) / 256;         // 391: 4 waves x 64 nodes each
    node_proj_mfma<<<nblocks, 256, 0, stream>>>(z, W1, b1, A, B, n_nodes);

    const int nchunks = E >> 6;                        // 50000
    const int split = (nchunks * 2) / 5;               // 20000 / 30000
    edge_kernel<<<2048, 256, 0, stream>>>(row, col, A, B, W2, b2, out, 0, split);
    edge_kernel<<<2048, 256, 0, stream>>>(row, col, A, B, W2, b2, out, split, nchunks);
}